// Round 12
// baseline (156.386 us; speedup 1.0000x reference)
//
#include <hip/hip_runtime.h>
#include <hip/hip_fp16.h>

// TensorFusion: out = tanh(tanh(tanh(fusion@W1+b1)@W2+b2)@W3+b3)
// fusion[b,(i,j,k)] = a_h[b,i]*v_h[b,j]*t_h[b,k], a_h=[1,a], 65^3 = 274625 cols.
// K decomposes into 4291 segments of K=64 (+ row 0 folded into tail bias).
// A[b,t] = scale[b]*inner[b,t] generated in-register (f16).
// ROUND 12: zero-LDS, 1-wave blocks, 16 waves/CU, TRUE depth-2 interleave.
// Wave tile = 64 rows x 16 cols; W1 frags loaded per-lane (8 strided dwords),
// ping-pong sets wA/wB ordered so every cvt has the other set + next scales
// in flight (counted vmcnt by construction, never 0). launch_bounds(64,4)
// -> <=128 VGPR, 4 waves/SIMD. Grid 8192 = 8 Mtiles x 4 Nquarters x 256
// chunks; chunk=bid&255 -> all siblings same XCD (L2 dedup); N-quarters read
// disjoint 64B sectors. Split-K f16 partials [chunk][512][64], tail fused MLP.

typedef _Float16 f16;
typedef f16 f16x8 __attribute__((ext_vector_type(8)));
typedef f16 f16x2 __attribute__((ext_vector_type(2)));
typedef __fp16 fp16x2 __attribute__((ext_vector_type(2)));
typedef float fx4 __attribute__((ext_vector_type(4)));

#define WS_AT    0
#define WS_VT    131072
#define WS_PART  262144   // f16 [256][512][64] = 16777216 B

__device__ __forceinline__ f16x2 pkrtz(float a, float b) {
  fp16x2 r = __builtin_amdgcn_cvt_pkrtz(a, b);
  return *(f16x2*)&r;
}

__device__ __forceinline__ void seg_decode(int s, int& ia, int& iv, int& isel,
                                           int& rowbase, int& rowstride) {
  if (s < 4096)      { int i = s >> 6, j = s & 63; ia = i; iv = j; isel = 0;
                       rowbase = (i+1)*4225 + (j+1)*65 + 1; rowstride = 1; }
  else if (s < 4160) { int i = s - 4096; ia = i; iv = -1; isel = 2;
                       rowbase = (i+1)*4225 + 65; rowstride = 65; }
  else if (s < 4224) { int i = s - 4160; ia = i; iv = -1; isel = 0;
                       rowbase = (i+1)*4225 + 1; rowstride = 1; }
  else if (s < 4288) { int j = s - 4224; ia = -1; iv = j; isel = 0;
                       rowbase = (j+1)*65 + 1; rowstride = 1; }
  else if (s == 4288){ ia = -1; iv = -1; isel = 1; rowbase = 4225; rowstride = 4225; }
  else if (s == 4289){ ia = -1; iv = -1; isel = 2; rowbase = 65;   rowstride = 65; }
  else if (s == 4290){ ia = -1; iv = -1; isel = 0; rowbase = 1;    rowstride = 1; }
  else               { ia = -2; iv = -1; isel = 0; rowbase = 1;    rowstride = 1; } // dummy: scale 0
}

__device__ __forceinline__ f16x8 cvt8(fx4 x0, fx4 x1) {
  f16x8 f;
  f[0]=(f16)x0[0]; f[1]=(f16)x0[1]; f[2]=(f16)x0[2]; f[3]=(f16)x0[3];
  f[4]=(f16)x1[0]; f[5]=(f16)x1[1]; f[6]=(f16)x1[2]; f[7]=(f16)x1[3];
  return f;
}

// ---------------- prep: aT/vT transposes (coalesced scale loads) ----------------
__global__ __launch_bounds__(256) void prep_kernel(
    const float* __restrict__ a, const float* __restrict__ v,
    float* __restrict__ aT, float* __restrict__ vT)
{
  int g = blockIdx.x * 256 + threadIdx.x;   // 2*32768 items
  int which = g >> 15;
  int idx = g & 32767;
  if (which == 0) aT[idx] = a[((idx & 511) << 6) + (idx >> 9)];  // aT[c][r]=a[r][c]
  else            vT[idx] = v[((idx & 511) << 6) + (idx >> 9)];
}

// ---------------- stage 1: the big implicit GEMM (1 wave, 64r x 16c) ----------------
__global__ __launch_bounds__(64, 4) void fusion_gemm(
    const float* __restrict__ W1,
    const float* __restrict__ aT, const float* __restrict__ vT,
    const float* __restrict__ a, const float* __restrict__ v, const float* __restrict__ l,
    f16* __restrict__ partials)
{
  const int lane = threadIdx.x;       // 0..63
  const int bid  = blockIdx.x;        // 0..8191
  const int chunk= bid & 255;         // XCD = chunk & 7 for ALL siblings
  const int q    = bid >> 8;
  const int nq   = q & 3;             // N-quarter (16 cols)
  const int mtile= q >> 2;            // 0..7 (64 rows)
  const int l15  = lane & 15;
  const int l4   = lane >> 4;         // 0..3
  const int segbase = chunk * 17;     // 256*17 = 4352 >= 4291
  const int row0 = mtile << 6;
  const int ncol = (nq << 4) + l15;   // this lane's W1 column

  // A-operand (l) fragments: rows row0 + mt*16 + l15, k = ks*32 + l4*8 + e
  f16x8 lfrag[4][2];
  #pragma unroll
  for (int mt = 0; mt < 4; ++mt) {
    int row = row0 + (mt << 4) + l15;
    #pragma unroll
    for (int ks = 0; ks < 2; ++ks) {
      const float* p = l + ((size_t)row << 6) + (ks << 5) + (l4 << 3);
      lfrag[mt][ks] = cvt8(*(const fx4*)p, *(const fx4*)(p + 4));
    }
  }

  fx4 acc[4] = {};                    // 16 VGPRs: acc[mt]
  float wA[8], wB[8];                 // ping-pong W1 staging (8 each)
  float sA[8], sB[8];                 // scales: [0..3]=spa, [4..7]=spv
  f16 ps0, ps1, ps2, ps3;

  // w[e] = W1[rb + (KS*32 + l4*8 + e)*rs][ncol]
#define ISSUE(W, T, KS) do {                                                  \
    int s_ = segbase + (T), ia_, iv_, is_, rb_, rs_;                          \
    seg_decode(s_, ia_, iv_, is_, rb_, rs_);                                  \
    const float* p_ = W1 + ((size_t)(rb_ + (((KS) << 5) + (l4 << 3)) * rs_) << 6) + ncol; \
    const size_t st_ = (size_t)(rs_ << 6);                                    \
    W[0] = p_[0];       W[1] = p_[st_];     W[2] = p_[st_ * 2];               \
    W[3] = p_[st_ * 3]; W[4] = p_[st_ * 4]; W[5] = p_[st_ * 5];               \
    W[6] = p_[st_ * 6]; W[7] = p_[st_ * 7];                                   \
    __builtin_amdgcn_sched_barrier(0);                                        \
  } while (0)

#define SCALELOAD(S, T) do {                                                  \
    int s_ = segbase + (T), ia_, iv_, is_, rb_, rs_;                          \
    seg_decode(s_, ia_, iv_, is_, rb_, rs_);                                  \
    _Pragma("unroll")                                                         \
    for (int mt_ = 0; mt_ < 4; ++mt_) {                                       \
      int r_ = row0 + (mt_ << 4) + l15;                                       \
      S[mt_]     = (ia_ >= 0) ? aT[(ia_ << 9) + r_] : (ia_ == -1 ? 1.0f : 0.0f); \
      S[4 + mt_] = (iv_ >= 0) ? vT[(iv_ << 9) + r_] : 1.0f;                   \
    }                                                                         \
    __builtin_amdgcn_sched_barrier(0);                                        \
  } while (0)

#define CVT(BF, W) do {                                                       \
    ((f16x2*)&BF)[0] = pkrtz(W[0], W[1]);                                     \
    ((f16x2*)&BF)[1] = pkrtz(W[2], W[3]);                                     \
    ((f16x2*)&BF)[2] = pkrtz(W[4], W[5]);                                     \
    ((f16x2*)&BF)[3] = pkrtz(W[6], W[7]);                                     \
  } while (0)

#define MFMAPH(T, KS, BF) do {                                                \
    int s_ = segbase + (T);                                                   \
    int isel_ = ((s_ >= 4096 && s_ < 4160) || s_ == 4289) ? 2                 \
              : (s_ == 4288 ? 1 : 0);                                         \
    _Pragma("unroll")                                                         \
    for (int mt_ = 0; mt_ < 4; ++mt_) {                                       \
      f16x8 lv_;                                                              \
      if (isel_ == 0) lv_ = lfrag[mt_][KS];                                   \
      else {                                                                  \
        const float* pp_ = (isel_ == 1 ? a : v)                               \
            + ((size_t)(row0 + (mt_ << 4) + l15) << 6) + ((KS) << 5) + (l4 << 3); \
        lv_ = cvt8(*(const fx4*)pp_, *(const fx4*)(pp_ + 4));                 \
      }                                                                       \
      f16 psv_ = (mt_ == 0 ? ps0 : mt_ == 1 ? ps1 : mt_ == 2 ? ps2 : ps3);    \
      f16x2 p2_ = { psv_, psv_ };                                             \
      f16x8 av_;                                                              \
      ((f16x2*)&av_)[0] = ((f16x2*)&lv_)[0] * p2_;                            \
      ((f16x2*)&av_)[1] = ((f16x2*)&lv_)[1] * p2_;                            \
      ((f16x2*)&av_)[2] = ((f16x2*)&lv_)[2] * p2_;                            \
      ((f16x2*)&av_)[3] = ((f16x2*)&lv_)[3] * p2_;                            \
      acc[mt_] = __builtin_amdgcn_mfma_f32_16x16x32_f16(av_, BF, acc[mt_], 0, 0, 0); \
    }                                                                         \
  } while (0)

  // BODY: every cvt has the OTHER w-set + next scales in flight (counted vmcnt)
#define BODY(T, SCUR, SNXT) do {                                              \
    f16x8 bfA_, bfB_;                                                         \
    ISSUE(wB, T, 1);                                                          \
    if ((T) < 16) SCALELOAD(SNXT, (T) + 1);                                   \
    ps0 = (f16)(SCUR[0] * SCUR[4]); ps1 = (f16)(SCUR[1] * SCUR[5]);           \
    ps2 = (f16)(SCUR[2] * SCUR[6]); ps3 = (f16)(SCUR[3] * SCUR[7]);           \
    CVT(bfA_, wA);                                                            \
    MFMAPH(T, 0, bfA_);                                                       \
    if ((T) < 16) ISSUE(wA, (T) + 1, 0);                                      \
    CVT(bfB_, wB);                                                            \
    MFMAPH(T, 1, bfB_);                                                       \
  } while (0)

  // prologue
  ISSUE(wA, 0, 0);
  SCALELOAD(sA, 0);

  #pragma unroll 1
  for (int tt = 0; tt < 8; ++tt) {
    BODY(tt * 2,     sA, sB);
    BODY(tt * 2 + 1, sB, sA);
  }
  BODY(16, sA, sB);
#undef ISSUE
#undef SCALELOAD
#undef CVT
#undef MFMAPH
#undef BODY

  // epilogue: f16 partials [chunk][row][n] (16 scalar stores/lane)
  #pragma unroll
  for (int mt = 0; mt < 4; ++mt)
    #pragma unroll
    for (int r = 0; r < 4; ++r) {
      int grow = row0 + (mt << 4) + (l4 << 2) + r;
      partials[((size_t)chunk << 15) + ((size_t)grow << 6) + ncol] = (f16)acc[mt][r];
    }
}

// ---------------- tail: reduce partials + bias + tanh + 2x 64x64 GEMM ----------------
__global__ __launch_bounds__(256) void tail_kernel(
    const f16* __restrict__ partials, const float* __restrict__ W1, const float* __restrict__ b1,
    const float* __restrict__ W2, const float* __restrict__ b2,
    const float* __restrict__ W3, const float* __restrict__ b3, float* __restrict__ out)
{
  __shared__ float red[4][64];
  __shared__ float hbuf[64];
  __shared__ float h2buf[64];
  const int row = blockIdx.x;          // 0..511
  const int t = threadIdx.x;
  const int q = t >> 6, n = t & 63;
  // partials element (chunk, row, n) at chunk*32768 + row*64 + n
  const f16* base = partials + ((size_t)row << 6) + n;

  float s0 = 0.f, s1 = 0.f, s2 = 0.f, s3 = 0.f;
  #pragma unroll 4
  for (int c = q; c < 256; c += 16) {
    s0 += (float)base[(size_t)c << 15];
    s1 += (float)base[(size_t)(c + 4) << 15];
    s2 += (float)base[(size_t)(c + 8) << 15];
    s3 += (float)base[(size_t)(c + 12) << 15];
  }
  red[q][n] = (s0 + s1) + (s2 + s3);
  __syncthreads();
  if (t < 64) {
    float acc = b1[t] + W1[t] + red[0][t] + red[1][t] + red[2][t] + red[3][t];
    hbuf[t] = tanhf(acc);              // W1[t] = row-0 (1*1*1) term
  }
  __syncthreads();
  if (t < 64) {
    float acc = b2[t];
    #pragma unroll 8
    for (int k = 0; k < 64; ++k) acc += hbuf[k] * W2[(k << 6) + t];
    h2buf[t] = tanhf(acc);
  }
  __syncthreads();
  if (t < 64) {
    float acc = b3[t];
    #pragma unroll 8
    for (int k = 0; k < 64; ++k) acc += h2buf[k] * W3[(k << 6) + t];
    out[(row << 6) + t] = tanhf(acc);
  }
}

extern "C" void kernel_launch(void* const* d_in, const int* in_sizes, int n_in,
                              void* d_out, int out_size, void* d_ws, size_t ws_size,
                              hipStream_t stream) {
  const float* l  = (const float*)d_in[0];
  const float* a  = (const float*)d_in[1];
  const float* v  = (const float*)d_in[2];
  const float* W1 = (const float*)d_in[3];
  const float* b1 = (const float*)d_in[4];
  const float* W2 = (const float*)d_in[5];
  const float* b2 = (const float*)d_in[6];
  const float* W3 = (const float*)d_in[7];
  const float* b3 = (const float*)d_in[8];
  float* out = (float*)d_out;

  char* ws = (char*)d_ws;
  float* aT = (float*)(ws + WS_AT);
  float* vT = (float*)(ws + WS_VT);
  f16* partials = (f16*)(ws + WS_PART);

  hipLaunchKernelGGL(prep_kernel, dim3(256), dim3(256), 0, stream, a, v, aT, vT);
  hipLaunchKernelGGL(fusion_gemm, dim3(8192), dim3(64), 0, stream,
                     W1, aT, vT, a, v, l, partials);
  hipLaunchKernelGGL(tail_kernel, dim3(512), dim3(256), 0, stream,
                     partials, W1, b1, W2, b2, W3, b3, out);
}